// Round 2
// baseline (2728.390 us; speedup 1.0000x reference)
//
#include <hip/hip_runtime.h>

// Problem constants: B=2, S=1024, D=512, H=8, L=6, V=32000, W=64, FF=2048, HD=64
// I/O dtype: float32 (per reference). Internal activations: bf16 (threshold 4.8e-2 allows it).
#define SEQ    1024
#define DIM    512
#define NHEAD  8
#define NLAYER 6
#define FFDIM  2048
#define HDIM   64
#define BATCH  2
#define VOCAB  32000
#define ROWS   (BATCH * SEQ)   // 2048 token rows

typedef __attribute__((ext_vector_type(8))) __bf16 bf16x8;
typedef __attribute__((ext_vector_type(4))) float  f32x4;

__device__ __forceinline__ unsigned short f2bf(float f) {
    unsigned int u = __float_as_uint(f);
    u += 0x7FFFu + ((u >> 16) & 1u);           // round-to-nearest-even
    return (unsigned short)(u >> 16);
}
__device__ __forceinline__ float bf2f(unsigned short u) {
    return __uint_as_float(((unsigned int)u) << 16);
}
__device__ __forceinline__ float lo_f(unsigned int u) { return __uint_as_float(u << 16); }
__device__ __forceinline__ float hi_f(unsigned int u) { return __uint_as_float(u & 0xFFFF0000u); }
__device__ __forceinline__ unsigned int pack2(float a, float b) {   // a -> low half
    return (unsigned int)f2bf(a) | ((unsigned int)f2bf(b) << 16);
}

// ---------------------------------------------------------------------------
// x[row, :] = bf16( emb_f32[ids[row], :] + sinusoidal_pos_enc(row % SEQ, :) )
// ---------------------------------------------------------------------------
__global__ __launch_bounds__(256) void embed_kernel(const int* __restrict__ ids,
                                                    const float* __restrict__ emb,
                                                    unsigned short* __restrict__ x) {
    int t8   = blockIdx.x * 256 + threadIdx.x;   // one thread = 8 elements
    int base = t8 * 8;
    int row  = base >> 9;        // / DIM
    int d0   = base & (DIM - 1);
    int s    = row & (SEQ - 1);
    int id   = ids[row];
    const float* er = emb + (size_t)id * DIM + d0;
    float4 ea = *(const float4*)(er);
    float4 eb = *(const float4*)(er + 4);
    float e[8] = {ea.x, ea.y, ea.z, ea.w, eb.x, eb.y, eb.z, eb.w};
    unsigned int ou[4];
#pragma unroll
    for (int m = 0; m < 4; ++m) {
        int de = d0 + 2 * m;                                     // even dim index
        float div = expf((float)de * -0.017988946039015984f);    // -ln(10000)/512
        float arg = (float)s * div;
        ou[m] = pack2(e[2 * m] + sinf(arg), e[2 * m + 1] + cosf(arg));
    }
    *(uint4*)(x + base) = make_uint4(ou[0], ou[1], ou[2], ou[3]);
}

// ---------------------------------------------------------------------------
// C[M,N] = A[M,K] @ W[N,K]^T (+ bias[N]); A bf16, W f32 (converted to bf16 in
// staging), fp32 MFMA accum; C bf16 (intermediate) or f32 (lm head).
// Block: 256 thr (4 waves, 2x2), tile 128x128, BK=64, MFMA 16x16x32 bf16.
// LDS rows padded 64->72 elems (144B stride: 16B-aligned, 2-way conflicts free).
// ---------------------------------------------------------------------------
template <bool OUT_F32>
__global__ __launch_bounds__(256) void gemm_kernel(const unsigned short* __restrict__ A,
                                                   const float* __restrict__ W,
                                                   const float* __restrict__ bias,
                                                   void* __restrict__ Cout,
                                                   int M, int N, int K) {
    __shared__ __align__(16) unsigned short As[128 * 72];
    __shared__ __align__(16) unsigned short Bs[128 * 72];
    const int tid  = threadIdx.x;
    const int m0   = blockIdx.y * 128;
    const int n0   = blockIdx.x * 128;
    const int lane = tid & 63;
    const int wv   = tid >> 6;
    const int wr   = wv >> 1, wc = wv & 1;       // wave's 64x64 quadrant
    const int frow = lane & 15, quad = lane >> 4;

    f32x4 acc[4][4] = {};

    const int sr = tid >> 3;          // staging row 0..31
    const int sc = (tid & 7) * 8;     // staging col group (8 elements)
    const unsigned short* Ag = A + (size_t)(m0 + sr) * K + sc;
    const float*          Wg = W + (size_t)(n0 + sr) * K + sc;

    for (int k0 = 0; k0 < K; k0 += 64) {
#pragma unroll
        for (int p = 0; p < 4; ++p) {
            *(uint4*)&As[(sr + p * 32) * 72 + sc] = *(const uint4*)(Ag + (size_t)(p * 32) * K + k0);
            const float* wp = Wg + (size_t)(p * 32) * K + k0;
            float4 wa = *(const float4*)(wp);
            float4 wb = *(const float4*)(wp + 4);
            *(uint4*)&Bs[(sr + p * 32) * 72 + sc] =
                make_uint4(pack2(wa.x, wa.y), pack2(wa.z, wa.w),
                           pack2(wb.x, wb.y), pack2(wb.z, wb.w));
        }
        __syncthreads();
#pragma unroll
        for (int kk = 0; kk < 64; kk += 32) {
            bf16x8 af[4], bfr[4];
#pragma unroll
            for (int t = 0; t < 4; ++t) {
                af[t]  = *(const bf16x8*)&As[(wr * 64 + t * 16 + frow) * 72 + kk + quad * 8];
                bfr[t] = *(const bf16x8*)&Bs[(wc * 64 + t * 16 + frow) * 72 + kk + quad * 8];
            }
#pragma unroll
            for (int am = 0; am < 4; ++am)
#pragma unroll
                for (int bn = 0; bn < 4; ++bn)
                    acc[am][bn] = __builtin_amdgcn_mfma_f32_16x16x32_bf16(af[am], bfr[bn], acc[am][bn], 0, 0, 0);
        }
        __syncthreads();
    }

    // epilogue: D row = (lane>>4)*4 + r, col = lane&15 (verified C/D layout)
#pragma unroll
    for (int am = 0; am < 4; ++am) {
#pragma unroll
        for (int bn = 0; bn < 4; ++bn) {
            int col  = n0 + wc * 64 + bn * 16 + frow;
            float bv = bias ? bias[col] : 0.0f;
#pragma unroll
            for (int r = 0; r < 4; ++r) {
                int row = m0 + wr * 64 + am * 16 + quad * 4 + r;
                if (OUT_F32) ((float*)Cout)[(size_t)row * N + col] = acc[am][bn][r] + bv;
                else ((unsigned short*)Cout)[(size_t)row * N + col] = f2bf(acc[am][bn][r] + bv);
            }
        }
    }
}

// ---------------------------------------------------------------------------
// Windowed attention: one wave per (b, h, i). win = (h+1)*64, keys j in
// [max(0,i-win+1), i]. qkv row layout (bf16 ws): [q(512) | k(512) | v(512)].
// ---------------------------------------------------------------------------
__global__ __launch_bounds__(256) void attn_kernel(const unsigned short* __restrict__ qkv,
                                                   unsigned short* __restrict__ out) {
    __shared__ float qs[4][64];
    const int tid = threadIdx.x;
    const int w   = tid >> 6, lane = tid & 63;
    const int gw  = blockIdx.x * 4 + w;
    const int b   = gw >> 13;            // / (H*S)
    const int h   = (gw >> 10) & 7;
    const int i   = gw & (SEQ - 1);

    const size_t qoff = ((size_t)(b * SEQ + i)) * (3 * DIM) + h * HDIM;
    qs[w][lane] = bf2f(qkv[qoff + lane]) * 0.125f;   // 1/sqrt(64) folded into q
    __syncthreads();

    const int win = (h + 1) * 64;
    int jstart = i - win + 1; if (jstart < 0) jstart = 0;
    const int nk = i - jstart + 1;               // 1..512

    float sc[8];
    float mx = -3.0e38f;
#pragma unroll
    for (int t = 0; t < 8; ++t) {
        int j = jstart + t * 64 + lane;
        float dot = -3.0e38f;
        if (j <= i) {
            const unsigned short* kr = qkv + ((size_t)(b * SEQ + j)) * (3 * DIM) + DIM + h * HDIM;
            dot = 0.0f;
#pragma unroll
            for (int dq = 0; dq < 8; ++dq) {
                uint4 kv = *(const uint4*)(kr + dq * 8);
                const float* q = &qs[w][dq * 8];
                dot += q[0] * lo_f(kv.x) + q[1] * hi_f(kv.x)
                     + q[2] * lo_f(kv.y) + q[3] * hi_f(kv.y)
                     + q[4] * lo_f(kv.z) + q[5] * hi_f(kv.z)
                     + q[6] * lo_f(kv.w) + q[7] * hi_f(kv.w);
            }
            mx = fmaxf(mx, dot);
        }
        sc[t] = dot;
    }
#pragma unroll
    for (int off = 32; off >= 1; off >>= 1) mx = fmaxf(mx, __shfl_xor(mx, off));

    float p[8];
    float sum = 0.0f;
#pragma unroll
    for (int t = 0; t < 8; ++t) { p[t] = expf(sc[t] - mx); sum += p[t]; }  // invalid -> 0
#pragma unroll
    for (int off = 32; off >= 1; off >>= 1) sum += __shfl_xor(sum, off);
    float inv = 1.0f / sum;
#pragma unroll
    for (int t = 0; t < 8; ++t) p[t] *= inv;

    const unsigned short* vb = qkv + ((size_t)(b * SEQ)) * (3 * DIM) + 2 * DIM + h * HDIM + lane;
    float acc = 0.0f;
#pragma unroll
    for (int t = 0; t < 8; ++t) {            // static t -> p[] stays in registers
        int cnt = nk - t * 64; if (cnt > 64) cnt = 64;
        int jb  = jstart + t * 64;
        for (int l = 0; l < cnt; ++l) {
            float pb = __shfl(p[t], l);      // uniform lane -> readlane broadcast
            acc += pb * bf2f(vb[(size_t)(jb + l) * (3 * DIM)]);
        }
    }
    out[((size_t)(b * SEQ + i)) * DIM + h * HDIM + lane] = f2bf(acc);
}

// ---------------------------------------------------------------------------
// out = bf16( LayerNorm(x (+ res)) * g + b ) — biased variance, eps 1e-5.
// x/res bf16 (ws); g/b f32 (global). One wave per row (512 elems, 8/lane).
// ---------------------------------------------------------------------------
__global__ __launch_bounds__(256) void ln_kernel(const unsigned short* __restrict__ xin,
                                                 const unsigned short* __restrict__ res,
                                                 const float* __restrict__ g,
                                                 const float* __restrict__ bta,
                                                 unsigned short* __restrict__ out) {
    const int tid = threadIdx.x;
    const int w   = tid >> 6, lane = tid & 63;
    const int row = blockIdx.x * 4 + w;
    const int c0  = lane * 8;
    const size_t base = (size_t)row * DIM + c0;

    uint4 xv = *(const uint4*)(xin + base);
    float v[8] = {lo_f(xv.x), hi_f(xv.x), lo_f(xv.y), hi_f(xv.y),
                  lo_f(xv.z), hi_f(xv.z), lo_f(xv.w), hi_f(xv.w)};
    if (res) {
        uint4 rv = *(const uint4*)(res + base);
        v[0] += lo_f(rv.x); v[1] += hi_f(rv.x); v[2] += lo_f(rv.y); v[3] += hi_f(rv.y);
        v[4] += lo_f(rv.z); v[5] += hi_f(rv.z); v[6] += lo_f(rv.w); v[7] += hi_f(rv.w);
    }
    float sum = 0.0f, sq = 0.0f;
#pragma unroll
    for (int t = 0; t < 8; ++t) { sum += v[t]; sq += v[t] * v[t]; }
#pragma unroll
    for (int off = 32; off >= 1; off >>= 1) { sum += __shfl_xor(sum, off); sq += __shfl_xor(sq, off); }
    float mean = sum * (1.0f / DIM);
    float var  = sq * (1.0f / DIM) - mean * mean;
    float rstd = rsqrtf(var + 1e-5f);

    float4 ga = *(const float4*)(g + c0);
    float4 gb = *(const float4*)(g + c0 + 4);
    float4 ba = *(const float4*)(bta + c0);
    float4 bb = *(const float4*)(bta + c0 + 4);
    float gf[8] = {ga.x, ga.y, ga.z, ga.w, gb.x, gb.y, gb.z, gb.w};
    float bf[8] = {ba.x, ba.y, ba.z, ba.w, bb.x, bb.y, bb.z, bb.w};
    unsigned int o[4];
#pragma unroll
    for (int m = 0; m < 4; ++m) {
        float a0 = (v[2 * m]     - mean) * rstd * gf[2 * m]     + bf[2 * m];
        float a1 = (v[2 * m + 1] - mean) * rstd * gf[2 * m + 1] + bf[2 * m + 1];
        o[m] = pack2(a0, a1);
    }
    *(uint4*)(out + base) = make_uint4(o[0], o[1], o[2], o[3]);
}

// ---------------------------------------------------------------------------
// SwiGLU: h[M, 4096] bf16 -> o[M, 2048] bf16; o = h[:, :2048] * silu(h[:, 2048:])
// ---------------------------------------------------------------------------
__global__ __launch_bounds__(256) void swiglu_kernel(const unsigned short* __restrict__ h,
                                                     unsigned short* __restrict__ o) {
    int t8   = blockIdx.x * 256 + threadIdx.x;
    int base = t8 * 8;
    int r = base >> 11;           // / FFDIM
    int c = base & (FFDIM - 1);
    const unsigned short* hr = h + (size_t)r * (2 * FFDIM);
    uint4 uv = *(const uint4*)(hr + c);
    uint4 gv = *(const uint4*)(hr + FFDIM + c);
    float u[8] = {lo_f(uv.x), hi_f(uv.x), lo_f(uv.y), hi_f(uv.y),
                  lo_f(uv.z), hi_f(uv.z), lo_f(uv.w), hi_f(uv.w)};
    float gg[8] = {lo_f(gv.x), hi_f(gv.x), lo_f(gv.y), hi_f(gv.y),
                   lo_f(gv.z), hi_f(gv.z), lo_f(gv.w), hi_f(gv.w)};
    unsigned int ov[4];
#pragma unroll
    for (int m = 0; m < 4; ++m) {
        float g0 = gg[2 * m],     s0 = g0 / (1.0f + expf(-g0));
        float g1 = gg[2 * m + 1], s1 = g1 / (1.0f + expf(-g1));
        ov[m] = pack2(u[2 * m] * s0, u[2 * m + 1] * s1);
    }
    *(uint4*)(o + (size_t)r * FFDIM + c) = make_uint4(ov[0], ov[1], ov[2], ov[3]);
}

// ---------------------------------------------------------------------------
extern "C" void kernel_launch(void* const* d_in, const int* in_sizes, int n_in,
                              void* d_out, int out_size, void* d_ws, size_t ws_size,
                              hipStream_t stream) {
    const int*   ids  = (const int*)d_in[0];
    const float* emb  = (const float*)d_in[1];
    const float* Wqkv = (const float*)d_in[2];
    const float* bqkv = (const float*)d_in[3];
    const float* Wo   = (const float*)d_in[4];
    const float* bo   = (const float*)d_in[5];
    const float* W1   = (const float*)d_in[6];
    const float* b1   = (const float*)d_in[7];
    const float* W2   = (const float*)d_in[8];
    const float* b2   = (const float*)d_in[9];
    const float* ln1g = (const float*)d_in[10];
    const float* ln1b = (const float*)d_in[11];
    const float* ln2g = (const float*)d_in[12];
    const float* ln2b = (const float*)d_in[13];
    const float* lnfg = (const float*)d_in[14];
    const float* lnfb = (const float*)d_in[15];

    unsigned short* x    = (unsigned short*)d_ws;            // [2048, 512]  bf16
    unsigned short* qkv  = x    + (size_t)ROWS * DIM;        // [2048, 1536]
    unsigned short* attn = qkv  + (size_t)ROWS * 3 * DIM;    // [2048, 512]
    unsigned short* proj = attn + (size_t)ROWS * DIM;        // [2048, 512]
    unsigned short* hbuf = proj + (size_t)ROWS * DIM;        // [2048, 4096]
    unsigned short* ffin = hbuf + (size_t)ROWS * 2 * FFDIM;  // [2048, 2048]
    // total: ~38 MB of ws

    embed_kernel<<<ROWS * DIM / (256 * 8), 256, 0, stream>>>(ids, emb, x);

    for (int l = 0; l < NLAYER; ++l) {
        gemm_kernel<false><<<dim3(12, 16), 256, 0, stream>>>(x, Wqkv + (size_t)l * 3 * DIM * DIM,
                                                             bqkv + l * 3 * DIM, qkv, ROWS, 3 * DIM, DIM);
        attn_kernel<<<BATCH * NHEAD * SEQ / 4, 256, 0, stream>>>(qkv, attn);
        gemm_kernel<false><<<dim3(4, 16), 256, 0, stream>>>(attn, Wo + (size_t)l * DIM * DIM,
                                                            bo + l * DIM, proj, ROWS, DIM, DIM);
        ln_kernel<<<ROWS / 4, 256, 0, stream>>>(x, proj, ln1g + l * DIM, ln1b + l * DIM, x);
        gemm_kernel<false><<<dim3(32, 16), 256, 0, stream>>>(x, W1 + (size_t)l * 2 * FFDIM * DIM,
                                                             b1 + l * 2 * FFDIM, hbuf, ROWS, 2 * FFDIM, DIM);
        swiglu_kernel<<<ROWS * FFDIM / (256 * 8), 256, 0, stream>>>(hbuf, ffin);
        gemm_kernel<false><<<dim3(4, 16), 256, 0, stream>>>(ffin, W2 + (size_t)l * DIM * FFDIM,
                                                            b2 + l * DIM, attn /*ffout*/, ROWS, DIM, FFDIM);
        ln_kernel<<<ROWS / 4, 256, 0, stream>>>(x, attn, ln2g + l * DIM, ln2b + l * DIM, x);
    }
    ln_kernel<<<ROWS / 4, 256, 0, stream>>>(x, nullptr, lnfg, lnfb, x);
    gemm_kernel<true><<<dim3(VOCAB / 128, 16), 256, 0, stream>>>(x, emb, nullptr,
                                                                 d_out, ROWS, VOCAB, DIM);
}